// Round 1
// baseline (266.791 us; speedup 1.0000x reference)
//
#include <hip/hip_runtime.h>
#include <stdint.h>

#define BATCH 256
#define DBLK  16          // d
#define OB    128         // hidden nodes per diagonal block (M)
#define NN    2048        // M*D

using bf16x8 = __attribute__((ext_vector_type(8))) __bf16;
using f32x4  = __attribute__((ext_vector_type(4))) float;

__device__ __forceinline__ unsigned short f2bf(float f) {
    union { float f; uint32_t u; } v; v.f = f;
    uint32_t u = v.u;
    uint32_t r = (u + 0x7fffu + ((u >> 16) & 1u)) >> 16;   // RNE
    return (unsigned short)r;
}

// log|tanh'(x)| = 2*(ln2 - x - softplus(-2x)), stable
__device__ __forceinline__ float log_tanh_grad(float x) {
    float z  = -2.f * x;
    float sp = fmaxf(z, 0.f) + log1pf(__expf(-fabsf(z)));
    return 2.f * (0.69314718055994531f - x - sp);
}

// ---------------- prep: convert both flows' W1 to bf16 (lower blocks only) ----
__global__ void k_convert(const float* __restrict__ Wa,
                          const float* __restrict__ Wb,
                          unsigned short* __restrict__ dst) {
    const int jj  = blockIdx.x;                 // 0..4095 (2 flows x 2048 rows)
    const int row = jj & (NN - 1);
    const float* src = ((jj < NN) ? Wa : Wb) + (size_t)row * NN;
    unsigned short* out = dst + (size_t)jj * NN;
    const int kend = ((row >> 7) + 1) * OB;     // block-lower-triangular extent
    for (int k = threadIdx.x * 4; k < kend; k += 256 * 4) {
        float4 v = *(const float4*)(src + k);
        ushort4 u;
        u.x = f2bf(v.x); u.y = f2bf(v.y); u.z = f2bf(v.z); u.w = f2bf(v.w);
        *(ushort4*)(out + k) = u;
    }
}

// ---------------- layer0: out0 = x @ W0^T + b0 ; h0=tanh ; g0 = log W0diag + lga ;
//                  rowwise max m over the 128-block, e0 = exp(g0 - m) --------------
__global__ void k_layer0(const float* __restrict__ x,
                         const float* __restrict__ W0,
                         const float* __restrict__ b0,
                         unsigned short* __restrict__ h0,
                         unsigned short* __restrict__ e0,
                         float* __restrict__ mmax) {
    const int dd = blockIdx.x;    // 0..15
    const int b  = blockIdx.y;    // 0..255
    const int o  = threadIdx.x;   // 0..127
    const int j  = dd * OB + o;

    __shared__ float xs[DBLK];
    __shared__ float red[OB];
    if (o < DBLK) xs[o] = x[b * DBLK + o];
    __syncthreads();

    const float* wrow = W0 + (size_t)j * DBLK;
    float s = b0[j];
    #pragma unroll
    for (int c = 0; c < DBLK; ++c) s += wrow[c] * xs[c];

    h0[(size_t)b * NN + j] = f2bf(tanhf(s));
    float g = logf(wrow[dd]) + log_tanh_grad(s);

    red[o] = g;
    __syncthreads();
    #pragma unroll
    for (int st = OB / 2; st > 0; st >>= 1) {
        if (o < st) red[o] = fmaxf(red[o], red[o + st]);
        __syncthreads();
    }
    float m = red[0];
    e0[(size_t)b * NN + j] = f2bf(__expf(g - m));
    if (o == 0) mmax[b * DBLK + dd] = m;
}

// ---------------- layer1: C = h0 @ W1^T + b1 over one dd block (K <= (dd+1)*128),
//                  fused grad matvec S = W1diag @ exp(g0-m); h1=tanh, g1=log S+m+lga
__global__ void k_layer1(const unsigned short* __restrict__ h0,
                         const unsigned short* __restrict__ W1b,
                         const float* __restrict__ b1,
                         const unsigned short* __restrict__ e0,
                         const float* __restrict__ mmax,
                         float* __restrict__ h1,
                         float* __restrict__ g1) {
    const int dd    = blockIdx.x;            // 0..15  (output column block)
    const int bt    = blockIdx.y;            // 0..3   (batch tile of 64)
    const int wave  = threadIdx.x >> 6;      // 0..3
    const int lane  = threadIdx.x & 63;
    const int brow0 = bt * 64 + wave * 16;   // wave's 16 batch rows
    const int arow  = brow0 + (lane & 15);
    const int koff  = (lane >> 4) * 8;
    const int ncol  = lane & 15;

    f32x4 acc[8], acc2[8];
    #pragma unroll
    for (int nt = 0; nt < 8; ++nt) {
        acc[nt]  = (f32x4){0.f, 0.f, 0.f, 0.f};
        acc2[nt] = (f32x4){0.f, 0.f, 0.f, 0.f};
    }

    const unsigned short* Ab = h0 + (size_t)arow * NN + koff;
    const unsigned short* Bb[8];
    #pragma unroll
    for (int nt = 0; nt < 8; ++nt)
        Bb[nt] = W1b + (size_t)(dd * OB + nt * 16 + ncol) * NN + koff;

    const int kend = (dd + 1) * OB;
    for (int k = 0; k < kend; k += 32) {
        bf16x8 a = *(const bf16x8*)(Ab + k);
        #pragma unroll
        for (int nt = 0; nt < 8; ++nt) {
            bf16x8 bb = *(const bf16x8*)(Bb[nt] + k);
            acc[nt] = __builtin_amdgcn_mfma_f32_16x16x32_bf16(a, bb, acc[nt], 0, 0, 0);
        }
    }

    // grad matvec over diagonal 128x128 block: A = exp(g0 - m) (bf16)
    const unsigned short* Eb = e0 + (size_t)arow * NN + koff;
    #pragma unroll
    for (int kk = 0; kk < OB; kk += 32) {
        const int k = dd * OB + kk;
        bf16x8 a = *(const bf16x8*)(Eb + k);
        #pragma unroll
        for (int nt = 0; nt < 8; ++nt) {
            bf16x8 bb = *(const bf16x8*)(Bb[nt] + k);
            acc2[nt] = __builtin_amdgcn_mfma_f32_16x16x32_bf16(a, bb, acc2[nt], 0, 0, 0);
        }
    }

    float mrow[4];
    #pragma unroll
    for (int r = 0; r < 4; ++r)
        mrow[r] = mmax[(brow0 + (lane >> 4) * 4 + r) * DBLK + dd];

    #pragma unroll
    for (int nt = 0; nt < 8; ++nt) {
        const int j = dd * OB + nt * 16 + ncol;
        const float bias = b1[j];
        #pragma unroll
        for (int r = 0; r < 4; ++r) {
            const int brow = brow0 + (lane >> 4) * 4 + r;
            float pre = acc[nt][r] + bias;
            h1[(size_t)brow * NN + j] = tanhf(pre);
            float gg = logf(acc2[nt][r]) + mrow[r] + log_tanh_grad(pre);
            g1[(size_t)brow * NN + j] = gg;
        }
    }
}

// ---------------- final: out2 = h1 @ W2^T ; gradF = lse(log W2diag + g1) ; ld ----
__global__ void k_final(const float* __restrict__ h1,
                        const float* __restrict__ g1,
                        const float* __restrict__ W2,
                        float* __restrict__ xout,
                        const float* __restrict__ ld_prev,
                        float* __restrict__ ld_out) {
    const int b    = blockIdx.x;
    const int t    = threadIdx.x;
    const int wave = t >> 6;
    const int lane = t & 63;

    __shared__ float sh[NN];
    __shared__ float sg[NN];
    __shared__ float gf[DBLK];
    for (int k = t; k < NN; k += 256) {
        sh[k] = h1[(size_t)b * NN + k];
        sg[k] = g1[(size_t)b * NN + k];
    }
    __syncthreads();

    #pragma unroll
    for (int q = 0; q < 4; ++q) {
        const int dd = wave * 4 + q;
        const float* w2r = W2 + (size_t)dd * NN;
        // out2[b,dd]
        const int kend = (dd + 1) * OB;
        float s = 0.f;
        for (int k = lane; k < kend; k += 64) s += w2r[k] * sh[k];
        #pragma unroll
        for (int off = 32; off > 0; off >>= 1) s += __shfl_xor(s, off);
        // final lse over the diagonal block of W2
        float v0 = sg[dd * OB + lane];
        float v1 = sg[dd * OB + 64 + lane];
        float m = fmaxf(v0, v1);
        #pragma unroll
        for (int off = 32; off > 0; off >>= 1) m = fmaxf(m, __shfl_xor(m, off));
        float e = __expf(v0 - m) * w2r[dd * OB + lane]
                + __expf(v1 - m) * w2r[dd * OB + 64 + lane];
        #pragma unroll
        for (int off = 32; off > 0; off >>= 1) e += __shfl_xor(e, off);
        if (lane == 0) {
            xout[b * DBLK + dd] = s;
            gf[dd] = logf(e) + m;
        }
    }
    __syncthreads();
    if (t == 0) {
        float ld = 0.f;
        #pragma unroll
        for (int dd = 0; dd < DBLK; ++dd) ld += gf[dd];
        if (ld_prev) ld += ld_prev[b];
        ld_out[b] = ld;
    }
}

extern "C" void kernel_launch(void* const* d_in, const int* in_sizes, int n_in,
                              void* d_out, int out_size, void* d_ws, size_t ws_size,
                              hipStream_t stream) {
    const float* inp   = (const float*)d_in[0];
    const float* W0[2] = {(const float*)d_in[1], (const float*)d_in[6]};
    const float* W1[2] = {(const float*)d_in[2], (const float*)d_in[7]};
    const float* W2[2] = {(const float*)d_in[3], (const float*)d_in[8]};
    const float* b0[2] = {(const float*)d_in[4], (const float*)d_in[9]};
    const float* b1[2] = {(const float*)d_in[5], (const float*)d_in[10]};

    char* w = (char*)d_ws;
    size_t off = 0;
    unsigned short* W1b = (unsigned short*)(w + off); off += (size_t)2 * NN * NN * 2; // 16 MB
    unsigned short* h0b = (unsigned short*)(w + off); off += (size_t)BATCH * NN * 2;  // 1 MB
    unsigned short* e0b = (unsigned short*)(w + off); off += (size_t)BATCH * NN * 2;  // 1 MB
    float* mmax = (float*)(w + off); off += (size_t)BATCH * DBLK * 4;
    float* h1   = (float*)(w + off); off += (size_t)BATCH * NN * 4;                   // 2 MB
    float* g1   = (float*)(w + off); off += (size_t)BATCH * NN * 4;                   // 2 MB
    float* x1   = (float*)(w + off); off += (size_t)BATCH * DBLK * 4;
    float* ld0  = (float*)(w + off); off += (size_t)BATCH * 4;

    float* out_final = (float*)d_out;            // (256,16)
    float* ld_final  = (float*)d_out + BATCH * DBLK;  // (256,)

    k_convert<<<dim3(2 * NN), dim3(256), 0, stream>>>(W1[0], W1[1], W1b);

    for (int f = 0; f < 2; ++f) {
        const float* xin = (f == 0) ? inp : x1;
        k_layer0<<<dim3(DBLK, BATCH), dim3(OB), 0, stream>>>(
            xin, W0[f], b0[f], h0b, e0b, mmax);
        k_layer1<<<dim3(DBLK, 4), dim3(256), 0, stream>>>(
            h0b, W1b + (size_t)f * NN * NN, b1[f], e0b, mmax, h1, g1);
        k_final<<<dim3(BATCH), dim3(256), 0, stream>>>(
            h1, g1, W2[f],
            (f == 0) ? x1 : out_final,
            (f == 0) ? nullptr : ld0,
            (f == 0) ? ld0 : ld_final);
    }
}

// Round 2
// 127.062 us; speedup vs baseline: 2.0997x; 2.0997x over previous
//
#include <hip/hip_runtime.h>
#include <stdint.h>

#define BATCH 256
#define DBLK  16          // d
#define OB    128         // hidden nodes per diagonal block (M)
#define NN    2048        // M*D

using bf16x8 = __attribute__((ext_vector_type(8))) __bf16;
using f32x4  = __attribute__((ext_vector_type(4))) float;

__device__ __forceinline__ unsigned short f2bf(float f) {
    union { float f; uint32_t u; } v; v.f = f;
    uint32_t u = v.u;
    uint32_t r = (u + 0x7fffu + ((u >> 16) & 1u)) >> 16;   // RNE
    return (unsigned short)r;
}

// log|tanh'(x)| = 2*(ln2 - x - softplus(-2x)), stable
__device__ __forceinline__ float log_tanh_grad(float x) {
    float z  = -2.f * x;
    float sp = fmaxf(z, 0.f) + log1pf(__expf(-fabsf(z)));
    return 2.f * (0.69314718055994531f - x - sp);
}

// ---------------- prep: convert both flows' W1 to bf16 (lower blocks only) ----
__global__ void k_convert(const float* __restrict__ Wa,
                          const float* __restrict__ Wb,
                          unsigned short* __restrict__ dst) {
    const int jj  = blockIdx.x;                 // 0..4095 (2 flows x 2048 rows)
    const int row = jj & (NN - 1);
    const float* src = ((jj < NN) ? Wa : Wb) + (size_t)row * NN;
    unsigned short* out = dst + (size_t)jj * NN;
    const int kend = ((row >> 7) + 1) * OB;     // block-lower-triangular extent
    for (int k = threadIdx.x * 4; k < kend; k += 256 * 4) {
        float4 v = *(const float4*)(src + k);
        ushort4 u;
        u.x = f2bf(v.x); u.y = f2bf(v.y); u.z = f2bf(v.z); u.w = f2bf(v.w);
        *(ushort4*)(out + k) = u;
    }
}

// ---------------- layer0: out0 = x @ W0^T + b0 ; h0=tanh ; g0 = log W0diag + lga ;
//                  rowwise max m over the 128-block, e0 = exp(g0 - m) --------------
__global__ void k_layer0(const float* __restrict__ x,
                         const float* __restrict__ W0,
                         const float* __restrict__ b0,
                         unsigned short* __restrict__ h0,
                         unsigned short* __restrict__ e0,
                         float* __restrict__ mmax) {
    const int dd   = blockIdx.x;    // 0..15
    const int b    = blockIdx.y;    // 0..255
    const int o    = threadIdx.x;   // 0..127
    const int wave = o >> 6;
    const int j    = dd * OB + o;

    // x row: broadcast float4 loads (all lanes same address -> L1/L2 broadcast)
    float4 xv0 = *(const float4*)(x + b * DBLK + 0);
    float4 xv1 = *(const float4*)(x + b * DBLK + 4);
    float4 xv2 = *(const float4*)(x + b * DBLK + 8);
    float4 xv3 = *(const float4*)(x + b * DBLK + 12);

    const float* wrow = W0 + (size_t)j * DBLK;
    float4 w0 = *(const float4*)(wrow + 0);
    float4 w1 = *(const float4*)(wrow + 4);
    float4 w2 = *(const float4*)(wrow + 8);
    float4 w3 = *(const float4*)(wrow + 12);

    float s = b0[j];
    s += w0.x * xv0.x + w0.y * xv0.y + w0.z * xv0.z + w0.w * xv0.w;
    s += w1.x * xv1.x + w1.y * xv1.y + w1.z * xv1.z + w1.w * xv1.w;
    s += w2.x * xv2.x + w2.y * xv2.y + w2.z * xv2.z + w2.w * xv2.w;
    s += w3.x * xv3.x + w3.y * xv3.y + w3.z * xv3.z + w3.w * xv3.w;

    h0[(size_t)b * NN + j] = f2bf(tanhf(s));
    const float* wd = (const float*)&w0;   // wrow[dd] = component dd of the row
    float diag = wrow[dd];
    (void)wd;
    float g = logf(diag) + log_tanh_grad(s);

    // max over the 128 outputs of this dd block: wave shuffle + 2-entry LDS
    float m = g;
    #pragma unroll
    for (int off = 32; off > 0; off >>= 1) m = fmaxf(m, __shfl_xor(m, off));
    __shared__ float wm[2];
    if ((o & 63) == 0) wm[wave] = m;
    __syncthreads();
    m = fmaxf(wm[0], wm[1]);

    e0[(size_t)b * NN + j] = f2bf(__expf(g - m));
    if (o == 0) mmax[b * DBLK + dd] = m;
}

// ---------------- layer1: C = h0 @ W1^T + b1 over one dd block (K <= (dd+1)*128),
//                  fused grad matvec S = W1diag @ exp(g0-m); h1=tanh, g1=log S+m+lga
//                  grid (dd=16, bt=16, ct=4), 64 threads (1 wave) per block:
//                  each wave owns a 16-row x 32-col output tile.
__global__ void k_layer1(const unsigned short* __restrict__ h0,
                         const unsigned short* __restrict__ W1b,
                         const float* __restrict__ b1,
                         const unsigned short* __restrict__ e0,
                         const float* __restrict__ mmax,
                         float* __restrict__ h1,
                         float* __restrict__ g1) {
    const int dd    = blockIdx.x;            // 0..15  (output column block)
    const int bt    = blockIdx.y;            // 0..15  (batch tile of 16)
    const int ct    = blockIdx.z;            // 0..3   (column quarter, 32 cols)
    const int lane  = threadIdx.x;           // 0..63
    const int brow0 = bt * 16;
    const int arow  = brow0 + (lane & 15);
    const int koff  = (lane >> 4) * 8;
    const int ncol  = lane & 15;
    const int col0  = dd * OB + ct * 32;

    f32x4 acc[2], acc2[2];
    #pragma unroll
    for (int nt = 0; nt < 2; ++nt) {
        acc[nt]  = (f32x4){0.f, 0.f, 0.f, 0.f};
        acc2[nt] = (f32x4){0.f, 0.f, 0.f, 0.f};
    }

    const unsigned short* Ab = h0 + (size_t)arow * NN + koff;
    const unsigned short* Bb[2];
    #pragma unroll
    for (int nt = 0; nt < 2; ++nt)
        Bb[nt] = W1b + (size_t)(col0 + nt * 16 + ncol) * NN + koff;

    const int kend = (dd + 1) * OB;
    for (int k = 0; k < kend; k += 32) {
        bf16x8 a = *(const bf16x8*)(Ab + k);
        #pragma unroll
        for (int nt = 0; nt < 2; ++nt) {
            bf16x8 bb = *(const bf16x8*)(Bb[nt] + k);
            acc[nt] = __builtin_amdgcn_mfma_f32_16x16x32_bf16(a, bb, acc[nt], 0, 0, 0);
        }
    }

    // grad matvec over diagonal 128x128 block: A = exp(g0 - m) (bf16)
    const unsigned short* Eb = e0 + (size_t)arow * NN + koff;
    #pragma unroll
    for (int kk = 0; kk < OB; kk += 32) {
        const int k = dd * OB + kk;
        bf16x8 a = *(const bf16x8*)(Eb + k);
        #pragma unroll
        for (int nt = 0; nt < 2; ++nt) {
            bf16x8 bb = *(const bf16x8*)(Bb[nt] + k);
            acc2[nt] = __builtin_amdgcn_mfma_f32_16x16x32_bf16(a, bb, acc2[nt], 0, 0, 0);
        }
    }

    float mrow[4];
    #pragma unroll
    for (int r = 0; r < 4; ++r)
        mrow[r] = mmax[(brow0 + (lane >> 4) * 4 + r) * DBLK + dd];

    #pragma unroll
    for (int nt = 0; nt < 2; ++nt) {
        const int j = col0 + nt * 16 + ncol;
        const float bias = b1[j];
        #pragma unroll
        for (int r = 0; r < 4; ++r) {
            const int brow = brow0 + (lane >> 4) * 4 + r;
            float pre = acc[nt][r] + bias;
            h1[(size_t)brow * NN + j] = tanhf(pre);
            float gg = logf(acc2[nt][r]) + mrow[r] + log_tanh_grad(pre);
            g1[(size_t)brow * NN + j] = gg;
        }
    }
}

// ---------------- final: out2 = h1 @ W2^T ; gradF = lse(log W2diag + g1) ; ld ----
__global__ void k_final(const float* __restrict__ h1,
                        const float* __restrict__ g1,
                        const float* __restrict__ W2,
                        float* __restrict__ xout,
                        const float* __restrict__ ld_prev,
                        float* __restrict__ ld_out) {
    const int b    = blockIdx.x;
    const int t    = threadIdx.x;
    const int wave = t >> 6;
    const int lane = t & 63;

    __shared__ float sh[NN];
    __shared__ float sg[NN];
    __shared__ float gf[DBLK];
    for (int k = t * 4; k < NN; k += 256 * 4) {
        *(float4*)(sh + k) = *(const float4*)(h1 + (size_t)b * NN + k);
        *(float4*)(sg + k) = *(const float4*)(g1 + (size_t)b * NN + k);
    }
    __syncthreads();

    #pragma unroll
    for (int q = 0; q < 4; ++q) {
        const int dd = wave * 4 + q;
        const float* w2r = W2 + (size_t)dd * NN;
        // out2[b,dd] — float4 dot over the lower-triangular extent
        const int kend = (dd + 1) * OB;
        float s = 0.f;
        for (int k = lane * 4; k < kend; k += 64 * 4) {
            float4 hv = *(const float4*)(sh + k);
            float4 wv = *(const float4*)(w2r + k);
            s += hv.x * wv.x + hv.y * wv.y + hv.z * wv.z + hv.w * wv.w;
        }
        #pragma unroll
        for (int off = 32; off > 0; off >>= 1) s += __shfl_xor(s, off);
        // final lse over the diagonal block of W2
        float v0 = sg[dd * OB + lane];
        float v1 = sg[dd * OB + 64 + lane];
        float m = fmaxf(v0, v1);
        #pragma unroll
        for (int off = 32; off > 0; off >>= 1) m = fmaxf(m, __shfl_xor(m, off));
        float e = __expf(v0 - m) * w2r[dd * OB + lane]
                + __expf(v1 - m) * w2r[dd * OB + 64 + lane];
        #pragma unroll
        for (int off = 32; off > 0; off >>= 1) e += __shfl_xor(e, off);
        if (lane == 0) {
            xout[b * DBLK + dd] = s;
            gf[dd] = logf(e) + m;
        }
    }
    __syncthreads();
    if (t == 0) {
        float ld = 0.f;
        #pragma unroll
        for (int dd = 0; dd < DBLK; ++dd) ld += gf[dd];
        if (ld_prev) ld += ld_prev[b];
        ld_out[b] = ld;
    }
}

extern "C" void kernel_launch(void* const* d_in, const int* in_sizes, int n_in,
                              void* d_out, int out_size, void* d_ws, size_t ws_size,
                              hipStream_t stream) {
    const float* inp   = (const float*)d_in[0];
    const float* W0[2] = {(const float*)d_in[1], (const float*)d_in[6]};
    const float* W1[2] = {(const float*)d_in[2], (const float*)d_in[7]};
    const float* W2[2] = {(const float*)d_in[3], (const float*)d_in[8]};
    const float* b0[2] = {(const float*)d_in[4], (const float*)d_in[9]};
    const float* b1[2] = {(const float*)d_in[5], (const float*)d_in[10]};

    char* w = (char*)d_ws;
    size_t off = 0;
    unsigned short* W1b = (unsigned short*)(w + off); off += (size_t)2 * NN * NN * 2; // 16 MB
    unsigned short* h0b = (unsigned short*)(w + off); off += (size_t)BATCH * NN * 2;  // 1 MB
    unsigned short* e0b = (unsigned short*)(w + off); off += (size_t)BATCH * NN * 2;  // 1 MB
    float* mmax = (float*)(w + off); off += (size_t)BATCH * DBLK * 4;
    float* h1   = (float*)(w + off); off += (size_t)BATCH * NN * 4;                   // 2 MB
    float* g1   = (float*)(w + off); off += (size_t)BATCH * NN * 4;                   // 2 MB
    float* x1   = (float*)(w + off); off += (size_t)BATCH * DBLK * 4;
    float* ld0  = (float*)(w + off); off += (size_t)BATCH * 4;

    float* out_final = (float*)d_out;            // (256,16)
    float* ld_final  = (float*)d_out + BATCH * DBLK;  // (256,)

    k_convert<<<dim3(2 * NN), dim3(256), 0, stream>>>(W1[0], W1[1], W1b);

    for (int f = 0; f < 2; ++f) {
        const float* xin = (f == 0) ? inp : x1;
        k_layer0<<<dim3(DBLK, BATCH), dim3(OB), 0, stream>>>(
            xin, W0[f], b0[f], h0b, e0b, mmax);
        k_layer1<<<dim3(DBLK, 16, 4), dim3(64), 0, stream>>>(
            h0b, W1b + (size_t)f * NN * NN, b1[f], e0b, mmax, h1, g1);
        k_final<<<dim3(BATCH), dim3(256), 0, stream>>>(
            h1, g1, W2[f],
            (f == 0) ? x1 : out_final,
            (f == 0) ? nullptr : ld0,
            (f == 0) ? ld0 : ld_final);
    }
}

// Round 3
// 121.406 us; speedup vs baseline: 2.1975x; 1.0466x over previous
//
#include <hip/hip_runtime.h>
#include <stdint.h>

#define BATCH 256
#define DBLK  16          // d
#define OB    128         // hidden nodes per diagonal block (M)
#define NN    2048        // M*D

using bf16x8  = __attribute__((ext_vector_type(8))) __bf16;
using f32x4   = __attribute__((ext_vector_type(4))) float;
using ushort8 = __attribute__((ext_vector_type(8))) unsigned short;

__device__ __forceinline__ unsigned short f2bf(float f) {
    union { float f; uint32_t u; } v; v.f = f;
    uint32_t u = v.u;
    uint32_t r = (u + 0x7fffu + ((u >> 16) & 1u)) >> 16;   // RNE
    return (unsigned short)r;
}

// log|tanh'(x)| = 2*(ln2 - x - softplus(-2x)), stable
__device__ __forceinline__ float log_tanh_grad(float x) {
    float z  = -2.f * x;
    float sp = fmaxf(z, 0.f) + log1pf(__expf(-fabsf(z)));
    return 2.f * (0.69314718055994531f - x - sp);
}

// ---- layer0 for one batch row, 256 threads: thread t -> outputs j=t*8..t*8+7
// (all inside dd = t>>4; the 16-lane group covering a dd-block does the max)
__device__ __forceinline__ void l0_block(const float* __restrict__ xs,   // 16 floats
                                         const float* __restrict__ W0,
                                         const float* __restrict__ b0,
                                         unsigned short* __restrict__ h0,
                                         unsigned short* __restrict__ e0,
                                         float* __restrict__ mmax,
                                         int b, int t) {
    const int j0 = t * 8;
    const int dd = t >> 4;
    float g[8];
    unsigned short hv[8];
    float lm = -1e30f;
    #pragma unroll
    for (int q = 0; q < 8; ++q) {
        const int j = j0 + q;
        const float* wrow = W0 + (size_t)j * DBLK;
        float s = b0[j];
        #pragma unroll
        for (int c = 0; c < DBLK; c += 4) {
            float4 wv = *(const float4*)(wrow + c);
            s += wv.x * xs[c] + wv.y * xs[c + 1] + wv.z * xs[c + 2] + wv.w * xs[c + 3];
        }
        hv[q] = f2bf(tanhf(s));
        g[q]  = logf(wrow[dd]) + log_tanh_grad(s);
        lm = fmaxf(lm, g[q]);
    }
    #pragma unroll
    for (int off = 1; off < 16; off <<= 1) lm = fmaxf(lm, __shfl_xor(lm, off));
    ushort8 hh, ee;
    #pragma unroll
    for (int q = 0; q < 8; ++q) {
        hh[q] = hv[q];
        ee[q] = f2bf(__expf(g[q] - lm));
    }
    *(ushort8*)(h0 + (size_t)b * NN + j0) = hh;
    *(ushort8*)(e0 + (size_t)b * NN + j0) = ee;
    if ((t & 15) == 0) mmax[b * DBLK + dd] = lm;
}

// ---- P1: blocks [0,4096): convert both W1 to bf16 (triangular extent only);
//          blocks [4096,4352): layer0 of flow 0 (one batch row per block)
__global__ void k_prep(const float* __restrict__ W1a,
                       const float* __restrict__ W1c,
                       unsigned short* __restrict__ W1bf,
                       const float* __restrict__ inp,
                       const float* __restrict__ W0,
                       const float* __restrict__ b0,
                       unsigned short* __restrict__ h0,
                       unsigned short* __restrict__ e0,
                       float* __restrict__ mmax) {
    const int gb = blockIdx.x;
    if (gb < 2 * NN) {
        const int row = gb & (NN - 1);
        const float* src = ((gb < NN) ? W1a : W1c) + (size_t)row * NN;
        unsigned short* out = W1bf + (size_t)gb * NN;
        const int kend = ((row >> 7) + 1) * OB;
        for (int k = threadIdx.x * 4; k < kend; k += 256 * 4) {
            float4 v = *(const float4*)(src + k);
            ushort4 u;
            u.x = f2bf(v.x); u.y = f2bf(v.y); u.z = f2bf(v.z); u.w = f2bf(v.w);
            *(ushort4*)(out + k) = u;
        }
    } else {
        const int b = gb - 2 * NN;
        l0_block(inp + (size_t)b * DBLK, W0, b0, h0, e0, mmax, b, threadIdx.x);
    }
}

// ---- P2/P4: layer1. grid (dd=16, bt=16, ct=4), 256 thr (4 waves).
// Tile = 16 batch rows x 32 cols. Waves split K 4 ways; LDS combine; fused epilogue.
__global__ void k_layer1(const unsigned short* __restrict__ h0,
                         const unsigned short* __restrict__ W1b,
                         const float* __restrict__ b1,
                         const unsigned short* __restrict__ e0,
                         const float* __restrict__ mmax,
                         float* __restrict__ h1,
                         float* __restrict__ g1) {
    const int dd    = blockIdx.x;
    const int bt    = blockIdx.y;
    const int ct    = blockIdx.z;
    const int w     = threadIdx.x >> 6;
    const int lane  = threadIdx.x & 63;
    const int brow0 = bt * 16;
    const int arow  = brow0 + (lane & 15);
    const int koff  = (lane >> 4) * 8;
    const int ncol  = lane & 15;
    const int col0  = dd * OB + ct * 32;

    f32x4 acc[2], acc2[2];
    #pragma unroll
    for (int nt = 0; nt < 2; ++nt) {
        acc[nt]  = (f32x4){0.f, 0.f, 0.f, 0.f};
        acc2[nt] = (f32x4){0.f, 0.f, 0.f, 0.f};
    }

    const unsigned short* Ab = h0 + (size_t)arow * NN + koff;
    const unsigned short* Bb[2];
    #pragma unroll
    for (int nt = 0; nt < 2; ++nt)
        Bb[nt] = W1b + (size_t)(col0 + nt * 16 + ncol) * NN + koff;

    // GEMM part: wave w covers k in [w*(dd+1)*32, (w+1)*(dd+1)*32)
    const int iters = dd + 1;
    const int kbase = w * iters * 32;
    for (int i = 0; i < iters; ++i) {
        const int k = kbase + i * 32;
        bf16x8 a = *(const bf16x8*)(Ab + k);
        #pragma unroll
        for (int nt = 0; nt < 2; ++nt) {
            bf16x8 bb = *(const bf16x8*)(Bb[nt] + k);
            acc[nt] = __builtin_amdgcn_mfma_f32_16x16x32_bf16(a, bb, acc[nt], 0, 0, 0);
        }
    }

    // grad matvec over the 128-wide diagonal block: wave w takes one 32-chunk
    {
        const int k2 = dd * OB + w * 32;
        bf16x8 a = *(const bf16x8*)(e0 + (size_t)arow * NN + koff + k2);
        #pragma unroll
        for (int nt = 0; nt < 2; ++nt) {
            bf16x8 bb = *(const bf16x8*)(Bb[nt] + k2);
            acc2[nt] = __builtin_amdgcn_mfma_f32_16x16x32_bf16(a, bb, acc2[nt], 0, 0, 0);
        }
    }

    __shared__ float ls1[4][2][64][4];
    __shared__ float ls2[4][2][64][4];
    #pragma unroll
    for (int nt = 0; nt < 2; ++nt) {
        *(f32x4*)&ls1[w][nt][lane][0] = acc[nt];
        *(f32x4*)&ls2[w][nt][lane][0] = acc2[nt];
    }
    __syncthreads();

    #pragma unroll
    for (int half = 0; half < 2; ++half) {
        const int o  = threadIdx.x + half * 256;   // 0..511 output index in tile
        const int rr = o >> 5;                     // 0..15 row in tile
        const int cc = o & 31;                     // 0..31 col in tile
        const int nt = cc >> 4;
        const int r  = rr & 3;
        const int ls = (rr >> 2) * 16 + (cc & 15);
        float S  = ls1[0][nt][ls][r] + ls1[1][nt][ls][r] + ls1[2][nt][ls][r] + ls1[3][nt][ls][r];
        float S2 = ls2[0][nt][ls][r] + ls2[1][nt][ls][r] + ls2[2][nt][ls][r] + ls2[3][nt][ls][r];
        const int j    = col0 + cc;
        const int brow = brow0 + rr;
        const float pre = S + b1[j];
        h1[(size_t)brow * NN + j] = tanhf(pre);
        g1[(size_t)brow * NN + j] = logf(S2) + mmax[brow * DBLK + dd] + log_tanh_grad(pre);
    }
}

// ---- final-layer compute for one batch row (256 threads). Fills sx[16] (= out row)
// and returns this flow's log-det contribution (valid in all threads).
__device__ __forceinline__ float final_compute(const float* __restrict__ h1,
                                               const float* __restrict__ g1,
                                               const float* __restrict__ W2,
                                               int b, int t,
                                               float* sh, float* sg, float* gf, float* sx) {
    const int wave = t >> 6;
    const int lane = t & 63;
    for (int k = t * 4; k < NN; k += 256 * 4) {
        *(float4*)(sh + k) = *(const float4*)(h1 + (size_t)b * NN + k);
        *(float4*)(sg + k) = *(const float4*)(g1 + (size_t)b * NN + k);
    }
    __syncthreads();

    #pragma unroll
    for (int q = 0; q < 4; ++q) {
        const int dd = wave * 4 + q;
        const float* w2r = W2 + (size_t)dd * NN;
        const int kend = (dd + 1) * OB;
        float s = 0.f;
        for (int k = lane * 4; k < kend; k += 64 * 4) {
            float4 hv = *(const float4*)(sh + k);
            float4 wv = *(const float4*)(w2r + k);
            s += hv.x * wv.x + hv.y * wv.y + hv.z * wv.z + hv.w * wv.w;
        }
        #pragma unroll
        for (int off = 32; off > 0; off >>= 1) s += __shfl_xor(s, off);
        float v0 = sg[dd * OB + lane];
        float v1 = sg[dd * OB + 64 + lane];
        float m = fmaxf(v0, v1);
        #pragma unroll
        for (int off = 32; off > 0; off >>= 1) m = fmaxf(m, __shfl_xor(m, off));
        float e = __expf(v0 - m) * w2r[dd * OB + lane]
                + __expf(v1 - m) * w2r[dd * OB + 64 + lane];
        #pragma unroll
        for (int off = 32; off > 0; off >>= 1) e += __shfl_xor(e, off);
        if (lane == 0) {
            sx[dd] = s;
            gf[dd] = logf(e) + m;
        }
    }
    __syncthreads();
    float ld = 0.f;
    #pragma unroll
    for (int dd = 0; dd < DBLK; ++dd) ld += gf[dd];
    return ld;
}

// ---- P3: final of flow 0 + layer0 of flow 1 (block b = batch row b)
__global__ void k_final0_l0(const float* __restrict__ h1,
                            const float* __restrict__ g1,
                            const float* __restrict__ W2,   // flow 0
                            const float* __restrict__ W0,   // flow 1
                            const float* __restrict__ b0,   // flow 1
                            unsigned short* __restrict__ h0,
                            unsigned short* __restrict__ e0,
                            float* __restrict__ mmax,
                            float* __restrict__ ld0) {
    __shared__ float sh[NN];
    __shared__ float sg[NN];
    __shared__ float gf[DBLK];
    __shared__ float sx[DBLK];
    const int b = blockIdx.x;
    const int t = threadIdx.x;
    float ld = final_compute(h1, g1, W2, b, t, sh, sg, gf, sx);
    if (t == 0) ld0[b] = ld;
    l0_block(sx, W0, b0, h0, e0, mmax, b, t);
}

// ---- P5: final of flow 1 -> d_out
__global__ void k_final1(const float* __restrict__ h1,
                         const float* __restrict__ g1,
                         const float* __restrict__ W2,   // flow 1
                         const float* __restrict__ ld0,
                         float* __restrict__ out_final,
                         float* __restrict__ ld_final) {
    __shared__ float sh[NN];
    __shared__ float sg[NN];
    __shared__ float gf[DBLK];
    __shared__ float sx[DBLK];
    const int b = blockIdx.x;
    const int t = threadIdx.x;
    float ld = final_compute(h1, g1, W2, b, t, sh, sg, gf, sx);
    if (t < DBLK) out_final[b * DBLK + t] = sx[t];
    if (t == 0) ld_final[b] = ld + ld0[b];
}

extern "C" void kernel_launch(void* const* d_in, const int* in_sizes, int n_in,
                              void* d_out, int out_size, void* d_ws, size_t ws_size,
                              hipStream_t stream) {
    const float* inp   = (const float*)d_in[0];
    const float* W0[2] = {(const float*)d_in[1], (const float*)d_in[6]};
    const float* W1[2] = {(const float*)d_in[2], (const float*)d_in[7]};
    const float* W2[2] = {(const float*)d_in[3], (const float*)d_in[8]};
    const float* b0[2] = {(const float*)d_in[4], (const float*)d_in[9]};
    const float* b1[2] = {(const float*)d_in[5], (const float*)d_in[10]};

    char* w = (char*)d_ws;
    size_t off = 0;
    unsigned short* W1bf = (unsigned short*)(w + off); off += (size_t)2 * NN * NN * 2; // 16 MB
    unsigned short* h0b  = (unsigned short*)(w + off); off += (size_t)BATCH * NN * 2;  // 1 MB
    unsigned short* e0b  = (unsigned short*)(w + off); off += (size_t)BATCH * NN * 2;  // 1 MB
    float* mmax = (float*)(w + off); off += (size_t)BATCH * DBLK * 4;
    float* h1   = (float*)(w + off); off += (size_t)BATCH * NN * 4;                    // 2 MB
    float* g1   = (float*)(w + off); off += (size_t)BATCH * NN * 4;                    // 2 MB
    float* ld0  = (float*)(w + off); off += (size_t)BATCH * 4;

    float* out_final = (float*)d_out;                 // (256,16)
    float* ld_final  = (float*)d_out + BATCH * DBLK;  // (256,)

    // P1: convert both W1 + layer0 of flow 0
    k_prep<<<dim3(2 * NN + BATCH), dim3(256), 0, stream>>>(
        W1[0], W1[1], W1bf, inp, W0[0], b0[0], h0b, e0b, mmax);

    // P2: layer1 flow 0
    k_layer1<<<dim3(DBLK, 16, 4), dim3(256), 0, stream>>>(
        h0b, W1bf, b1[0], e0b, mmax, h1, g1);

    // P3: final flow 0 + layer0 flow 1
    k_final0_l0<<<dim3(BATCH), dim3(256), 0, stream>>>(
        h1, g1, W2[0], W0[1], b0[1], h0b, e0b, mmax, ld0);

    // P4: layer1 flow 1
    k_layer1<<<dim3(DBLK, 16, 4), dim3(256), 0, stream>>>(
        h0b, W1bf + (size_t)NN * NN, b1[1], e0b, mmax, h1, g1);

    // P5: final flow 1
    k_final1<<<dim3(BATCH), dim3(256), 0, stream>>>(
        h1, g1, W2[1], ld0, out_final, ld_final);
}

// Round 4
// 104.000 us; speedup vs baseline: 2.5653x; 1.1674x over previous
//
#include <hip/hip_runtime.h>
#include <stdint.h>

#define BATCH 256
#define DBLK  16          // d
#define OB    128         // hidden nodes per diagonal block (M)
#define NN    2048        // M*D
#define NCONV 1024        // convert blocks in k_prep

using bf16x8  = __attribute__((ext_vector_type(8))) __bf16;
using f32x4   = __attribute__((ext_vector_type(4))) float;
using ushort8 = __attribute__((ext_vector_type(8))) unsigned short;

__device__ __forceinline__ unsigned short f2bf(float f) {
    union { float f; uint32_t u; } v; v.f = f;
    uint32_t u = v.u;
    uint32_t r = (u + 0x7fffu + ((u >> 16) & 1u)) >> 16;   // RNE
    return (unsigned short)r;
}

// log|tanh'(x)| = 2*(ln2 - x - softplus(-2x)), stable
__device__ __forceinline__ float log_tanh_grad(float x) {
    float z  = -2.f * x;
    float sp = fmaxf(z, 0.f) + log1pf(__expf(-fabsf(z)));
    return 2.f * (0.69314718055994531f - x - sp);
}

// ---- layer0 for one batch row, 256 threads: thread t -> outputs j=t*8..t*8+7
__device__ __forceinline__ void l0_block(const float* __restrict__ xs,   // 16 floats
                                         const float* __restrict__ W0,
                                         const float* __restrict__ b0,
                                         unsigned short* __restrict__ h0,
                                         unsigned short* __restrict__ e0,
                                         float* __restrict__ mmax,
                                         int b, int t) {
    const int j0 = t * 8;
    const int dd = t >> 4;
    float g[8];
    unsigned short hv[8];
    float lm = -1e30f;
    #pragma unroll
    for (int q = 0; q < 8; ++q) {
        const int j = j0 + q;
        const float* wrow = W0 + (size_t)j * DBLK;
        float s = b0[j];
        #pragma unroll
        for (int c = 0; c < DBLK; c += 4) {
            float4 wv = *(const float4*)(wrow + c);
            s += wv.x * xs[c] + wv.y * xs[c + 1] + wv.z * xs[c + 2] + wv.w * xs[c + 3];
        }
        hv[q] = f2bf(tanhf(s));
        g[q]  = logf(wrow[dd]) + log_tanh_grad(s);
        lm = fmaxf(lm, g[q]);
    }
    #pragma unroll
    for (int off = 1; off < 16; off <<= 1) lm = fmaxf(lm, __shfl_xor(lm, off));
    ushort8 hh, ee;
    #pragma unroll
    for (int q = 0; q < 8; ++q) {
        hh[q] = hv[q];
        ee[q] = f2bf(__expf(g[q] - lm));
    }
    *(ushort8*)(h0 + (size_t)b * NN + j0) = hh;
    *(ushort8*)(e0 + (size_t)b * NN + j0) = ee;
    if ((t & 15) == 0) mmax[b * DBLK + dd] = lm;
}

__device__ __forceinline__ void conv_row(const float* __restrict__ src,
                                         unsigned short* __restrict__ out,
                                         int row, int t) {
    const int kend = ((row >> 7) + 1) * OB;     // triangular extent, mult of 128
    const int k = t * 8;
    if (k < kend) {
        float4 v0 = *(const float4*)(src + k);
        float4 v1 = *(const float4*)(src + k + 4);
        ushort8 u;
        u[0] = f2bf(v0.x); u[1] = f2bf(v0.y); u[2] = f2bf(v0.z); u[3] = f2bf(v0.w);
        u[4] = f2bf(v1.x); u[5] = f2bf(v1.y); u[6] = f2bf(v1.z); u[7] = f2bf(v1.w);
        *(ushort8*)(out + k) = u;
    }
}

// ---- P1: blocks [0,NCONV): convert both W1 to bf16 — block b does rows
//          {b, 2047-b} of each flow (constant total work per block);
//          blocks [NCONV, NCONV+256): layer0 of flow 0 (one batch row per block)
__global__ void k_prep(const float* __restrict__ W1a,
                       const float* __restrict__ W1c,
                       unsigned short* __restrict__ W1bf,
                       const float* __restrict__ inp,
                       const float* __restrict__ W0,
                       const float* __restrict__ b0,
                       unsigned short* __restrict__ h0,
                       unsigned short* __restrict__ e0,
                       float* __restrict__ mmax) {
    const int gb = blockIdx.x;
    const int t  = threadIdx.x;
    if (gb < NCONV) {
        const int r0 = gb;
        const int r1 = NN - 1 - gb;
        conv_row(W1a + (size_t)r0 * NN, W1bf + (size_t)r0 * NN,            r0, t);
        conv_row(W1a + (size_t)r1 * NN, W1bf + (size_t)r1 * NN,            r1, t);
        conv_row(W1c + (size_t)r0 * NN, W1bf + (size_t)(NN + r0) * NN,     r0, t);
        conv_row(W1c + (size_t)r1 * NN, W1bf + (size_t)(NN + r1) * NN,     r1, t);
    } else {
        const int b = gb - NCONV;
        l0_block(inp + (size_t)b * DBLK, W0, b0, h0, e0, mmax, b, t);
    }
}

// ---- P2/P4: layer1. grid (dd=16, bt=16, ct=4), 256 thr (4 waves).
// Tile = 16 batch rows x 32 cols. Waves split K 4 ways; LDS combine; fused epilogue.
__global__ void k_layer1(const unsigned short* __restrict__ h0,
                         const unsigned short* __restrict__ W1b,
                         const float* __restrict__ b1,
                         const unsigned short* __restrict__ e0,
                         const float* __restrict__ mmax,
                         float* __restrict__ h1,
                         float* __restrict__ g1) {
    const int dd    = blockIdx.x;
    const int bt    = blockIdx.y;
    const int ct    = blockIdx.z;
    const int w     = threadIdx.x >> 6;
    const int lane  = threadIdx.x & 63;
    const int brow0 = bt * 16;
    const int arow  = brow0 + (lane & 15);
    const int koff  = (lane >> 4) * 8;
    const int ncol  = lane & 15;
    const int col0  = dd * OB + ct * 32;

    f32x4 acc[2], acc2[2];
    #pragma unroll
    for (int nt = 0; nt < 2; ++nt) {
        acc[nt]  = (f32x4){0.f, 0.f, 0.f, 0.f};
        acc2[nt] = (f32x4){0.f, 0.f, 0.f, 0.f};
    }

    const unsigned short* Ab = h0 + (size_t)arow * NN + koff;
    const unsigned short* Bb[2];
    #pragma unroll
    for (int nt = 0; nt < 2; ++nt)
        Bb[nt] = W1b + (size_t)(col0 + nt * 16 + ncol) * NN + koff;

    // GEMM part: wave w covers k in [w*(dd+1)*32, (w+1)*(dd+1)*32)
    const int iters = dd + 1;
    const int kbase = w * iters * 32;
    for (int i = 0; i < iters; ++i) {
        const int k = kbase + i * 32;
        bf16x8 a = *(const bf16x8*)(Ab + k);
        #pragma unroll
        for (int nt = 0; nt < 2; ++nt) {
            bf16x8 bb = *(const bf16x8*)(Bb[nt] + k);
            acc[nt] = __builtin_amdgcn_mfma_f32_16x16x32_bf16(a, bb, acc[nt], 0, 0, 0);
        }
    }

    // grad matvec over the 128-wide diagonal block: wave w takes one 32-chunk
    {
        const int k2 = dd * OB + w * 32;
        bf16x8 a = *(const bf16x8*)(e0 + (size_t)arow * NN + koff + k2);
        #pragma unroll
        for (int nt = 0; nt < 2; ++nt) {
            bf16x8 bb = *(const bf16x8*)(Bb[nt] + k2);
            acc2[nt] = __builtin_amdgcn_mfma_f32_16x16x32_bf16(a, bb, acc2[nt], 0, 0, 0);
        }
    }

    __shared__ float ls1[4][2][64][4];
    __shared__ float ls2[4][2][64][4];
    #pragma unroll
    for (int nt = 0; nt < 2; ++nt) {
        *(f32x4*)&ls1[w][nt][lane][0] = acc[nt];
        *(f32x4*)&ls2[w][nt][lane][0] = acc2[nt];
    }
    __syncthreads();

    #pragma unroll
    for (int half = 0; half < 2; ++half) {
        const int o  = threadIdx.x + half * 256;   // 0..511 output index in tile
        const int rr = o >> 5;                     // 0..15 row in tile
        const int cc = o & 31;                     // 0..31 col in tile
        const int nt = cc >> 4;
        const int r  = rr & 3;
        const int ls = (rr >> 2) * 16 + (cc & 15);
        float S  = ls1[0][nt][ls][r] + ls1[1][nt][ls][r] + ls1[2][nt][ls][r] + ls1[3][nt][ls][r];
        float S2 = ls2[0][nt][ls][r] + ls2[1][nt][ls][r] + ls2[2][nt][ls][r] + ls2[3][nt][ls][r];
        const int j    = col0 + cc;
        const int brow = brow0 + rr;
        const float pre = S + b1[j];
        h1[(size_t)brow * NN + j] = tanhf(pre);
        g1[(size_t)brow * NN + j] = logf(S2) + mmax[brow * DBLK + dd] + log_tanh_grad(pre);
    }
}

// ---- final-layer compute for one batch row (256 threads). Fills sx[16] (= out row)
// and returns this flow's log-det contribution (valid in all threads).
// g1 has no reuse across dds -> read straight from L2, no LDS staging.
__device__ __forceinline__ float final_compute(const float* __restrict__ h1,
                                               const float* __restrict__ g1,
                                               const float* __restrict__ W2,
                                               int b, int t,
                                               float* sh, float* gf, float* sx) {
    const int wave = t >> 6;
    const int lane = t & 63;
    for (int k = t * 4; k < NN; k += 256 * 4)
        *(float4*)(sh + k) = *(const float4*)(h1 + (size_t)b * NN + k);
    __syncthreads();

    #pragma unroll
    for (int q = 0; q < 4; ++q) {
        const int dd = wave * 4 + q;
        const float* w2r = W2 + (size_t)dd * NN;
        const int kend = (dd + 1) * OB;
        float s = 0.f;
        for (int k = lane * 4; k < kend; k += 64 * 4) {
            float4 hv = *(const float4*)(sh + k);
            float4 wv = *(const float4*)(w2r + k);
            s += hv.x * wv.x + hv.y * wv.y + hv.z * wv.z + hv.w * wv.w;
        }
        #pragma unroll
        for (int off = 32; off > 0; off >>= 1) s += __shfl_xor(s, off);
        float v0 = g1[(size_t)b * NN + dd * OB + lane];
        float v1 = g1[(size_t)b * NN + dd * OB + 64 + lane];
        float m = fmaxf(v0, v1);
        #pragma unroll
        for (int off = 32; off > 0; off >>= 1) m = fmaxf(m, __shfl_xor(m, off));
        float e = __expf(v0 - m) * w2r[dd * OB + lane]
                + __expf(v1 - m) * w2r[dd * OB + 64 + lane];
        #pragma unroll
        for (int off = 32; off > 0; off >>= 1) e += __shfl_xor(e, off);
        if (lane == 0) {
            sx[dd] = s;
            gf[dd] = logf(e) + m;
        }
    }
    __syncthreads();
    float ld = 0.f;
    #pragma unroll
    for (int dd = 0; dd < DBLK; ++dd) ld += gf[dd];
    return ld;
}

// ---- P3: final of flow 0 + layer0 of flow 1 (block b = batch row b)
__global__ void k_final0_l0(const float* __restrict__ h1,
                            const float* __restrict__ g1,
                            const float* __restrict__ W2,   // flow 0
                            const float* __restrict__ W0,   // flow 1
                            const float* __restrict__ b0,   // flow 1
                            unsigned short* __restrict__ h0,
                            unsigned short* __restrict__ e0,
                            float* __restrict__ mmax,
                            float* __restrict__ ld0) {
    __shared__ float sh[NN];
    __shared__ float gf[DBLK];
    __shared__ float sx[DBLK];
    const int b = blockIdx.x;
    const int t = threadIdx.x;
    float ld = final_compute(h1, g1, W2, b, t, sh, gf, sx);
    if (t == 0) ld0[b] = ld;
    l0_block(sx, W0, b0, h0, e0, mmax, b, t);
}

// ---- P5: final of flow 1 -> d_out
__global__ void k_final1(const float* __restrict__ h1,
                         const float* __restrict__ g1,
                         const float* __restrict__ W2,   // flow 1
                         const float* __restrict__ ld0,
                         float* __restrict__ out_final,
                         float* __restrict__ ld_final) {
    __shared__ float sh[NN];
    __shared__ float gf[DBLK];
    __shared__ float sx[DBLK];
    const int b = blockIdx.x;
    const int t = threadIdx.x;
    float ld = final_compute(h1, g1, W2, b, t, sh, gf, sx);
    if (t < DBLK) out_final[b * DBLK + t] = sx[t];
    if (t == 0) ld_final[b] = ld + ld0[b];
}

extern "C" void kernel_launch(void* const* d_in, const int* in_sizes, int n_in,
                              void* d_out, int out_size, void* d_ws, size_t ws_size,
                              hipStream_t stream) {
    const float* inp   = (const float*)d_in[0];
    const float* W0[2] = {(const float*)d_in[1], (const float*)d_in[6]};
    const float* W1[2] = {(const float*)d_in[2], (const float*)d_in[7]};
    const float* W2[2] = {(const float*)d_in[3], (const float*)d_in[8]};
    const float* b0[2] = {(const float*)d_in[4], (const float*)d_in[9]};
    const float* b1[2] = {(const float*)d_in[5], (const float*)d_in[10]};

    char* w = (char*)d_ws;
    size_t off = 0;
    unsigned short* W1bf = (unsigned short*)(w + off); off += (size_t)2 * NN * NN * 2; // 16 MB
    unsigned short* h0b  = (unsigned short*)(w + off); off += (size_t)BATCH * NN * 2;  // 1 MB
    unsigned short* e0b  = (unsigned short*)(w + off); off += (size_t)BATCH * NN * 2;  // 1 MB
    float* mmax = (float*)(w + off); off += (size_t)BATCH * DBLK * 4;
    float* h1   = (float*)(w + off); off += (size_t)BATCH * NN * 4;                    // 2 MB
    float* g1   = (float*)(w + off); off += (size_t)BATCH * NN * 4;                    // 2 MB
    float* ld0  = (float*)(w + off); off += (size_t)BATCH * 4;

    float* out_final = (float*)d_out;                 // (256,16)
    float* ld_final  = (float*)d_out + BATCH * DBLK;  // (256,)

    // P1: convert both W1 + layer0 of flow 0
    k_prep<<<dim3(NCONV + BATCH), dim3(256), 0, stream>>>(
        W1[0], W1[1], W1bf, inp, W0[0], b0[0], h0b, e0b, mmax);

    // P2: layer1 flow 0
    k_layer1<<<dim3(DBLK, 16, 4), dim3(256), 0, stream>>>(
        h0b, W1bf, b1[0], e0b, mmax, h1, g1);

    // P3: final flow 0 + layer0 flow 1
    k_final0_l0<<<dim3(BATCH), dim3(256), 0, stream>>>(
        h1, g1, W2[0], W0[1], b0[1], h0b, e0b, mmax, ld0);

    // P4: layer1 flow 1
    k_layer1<<<dim3(DBLK, 16, 4), dim3(256), 0, stream>>>(
        h0b, W1bf + (size_t)NN * NN, b1[1], e0b, mmax, h1, g1);

    // P5: final flow 1
    k_final1<<<dim3(BATCH), dim3(256), 0, stream>>>(
        h1, g1, W2[1], ld0, out_final, ld_final);
}

// Round 5
// 102.239 us; speedup vs baseline: 2.6095x; 1.0172x over previous
//
#include <hip/hip_runtime.h>
#include <stdint.h>

#define BATCH 256
#define DBLK  16          // d
#define OB    128         // hidden nodes per diagonal block (M)
#define NN    2048        // M*D
#define NCONV 1024        // convert blocks in k_prep

using bf16x8  = __attribute__((ext_vector_type(8))) __bf16;
using f32x4   = __attribute__((ext_vector_type(4))) float;
using ushort8 = __attribute__((ext_vector_type(8))) unsigned short;

__device__ __forceinline__ unsigned short f2bf(float f) {
    union { float f; uint32_t u; } v; v.f = f;
    uint32_t u = v.u;
    uint32_t r = (u + 0x7fffu + ((u >> 16) & 1u)) >> 16;   // RNE
    return (unsigned short)r;
}

__device__ __forceinline__ float bf2f(unsigned short h) {
    union { uint32_t u; float f; } v; v.u = ((uint32_t)h) << 16;
    return v.f;
}

// log|tanh'(x)| = 2*(ln2 - x - softplus(-2x)), stable
__device__ __forceinline__ float log_tanh_grad(float x) {
    float z  = -2.f * x;
    float sp = fmaxf(z, 0.f) + log1pf(__expf(-fabsf(z)));
    return 2.f * (0.69314718055994531f - x - sp);
}

// ---- layer0 for one batch row, 256 threads: thread t -> outputs j=t*8..t*8+7
__device__ __forceinline__ void l0_block(const float* __restrict__ xs,   // 16 floats
                                         const float* __restrict__ W0,
                                         const float* __restrict__ b0,
                                         unsigned short* __restrict__ h0,
                                         unsigned short* __restrict__ e0,
                                         float* __restrict__ mmax,
                                         int b, int t) {
    const int j0 = t * 8;
    const int dd = t >> 4;
    float g[8];
    unsigned short hv[8];
    float lm = -1e30f;
    #pragma unroll
    for (int q = 0; q < 8; ++q) {
        const int j = j0 + q;
        const float* wrow = W0 + (size_t)j * DBLK;
        float s = b0[j];
        #pragma unroll
        for (int c = 0; c < DBLK; c += 4) {
            float4 wv = *(const float4*)(wrow + c);
            s += wv.x * xs[c] + wv.y * xs[c + 1] + wv.z * xs[c + 2] + wv.w * xs[c + 3];
        }
        hv[q] = f2bf(tanhf(s));
        g[q]  = logf(wrow[dd]) + log_tanh_grad(s);
        lm = fmaxf(lm, g[q]);
    }
    #pragma unroll
    for (int off = 1; off < 16; off <<= 1) lm = fmaxf(lm, __shfl_xor(lm, off));
    ushort8 hh, ee;
    #pragma unroll
    for (int q = 0; q < 8; ++q) {
        hh[q] = hv[q];
        ee[q] = f2bf(__expf(g[q] - lm));
    }
    *(ushort8*)(h0 + (size_t)b * NN + j0) = hh;
    *(ushort8*)(e0 + (size_t)b * NN + j0) = ee;
    if ((t & 15) == 0) mmax[b * DBLK + dd] = lm;
}

__device__ __forceinline__ void conv_row(const float* __restrict__ src,
                                         unsigned short* __restrict__ out,
                                         int row, int t) {
    const int kend = ((row >> 7) + 1) * OB;     // triangular extent, mult of 128
    const int k = t * 8;
    if (k < kend) {
        float4 v0 = *(const float4*)(src + k);
        float4 v1 = *(const float4*)(src + k + 4);
        ushort8 u;
        u[0] = f2bf(v0.x); u[1] = f2bf(v0.y); u[2] = f2bf(v0.z); u[3] = f2bf(v0.w);
        u[4] = f2bf(v1.x); u[5] = f2bf(v1.y); u[6] = f2bf(v1.z); u[7] = f2bf(v1.w);
        *(ushort8*)(out + k) = u;
    }
}

// ---- P1: blocks [0,NCONV): convert both W1 to bf16 — block b does rows
//          {b, 2047-b} of each flow; blocks [NCONV, NCONV+256): layer0 of flow 0
__global__ void k_prep(const float* __restrict__ W1a,
                       const float* __restrict__ W1c,
                       unsigned short* __restrict__ W1bf,
                       const float* __restrict__ inp,
                       const float* __restrict__ W0,
                       const float* __restrict__ b0,
                       unsigned short* __restrict__ h0,
                       unsigned short* __restrict__ e0,
                       float* __restrict__ mmax) {
    const int gb = blockIdx.x;
    const int t  = threadIdx.x;
    if (gb < NCONV) {
        const int r0 = gb;
        const int r1 = NN - 1 - gb;
        conv_row(W1a + (size_t)r0 * NN, W1bf + (size_t)r0 * NN,            r0, t);
        conv_row(W1a + (size_t)r1 * NN, W1bf + (size_t)r1 * NN,            r1, t);
        conv_row(W1c + (size_t)r0 * NN, W1bf + (size_t)(NN + r0) * NN,     r0, t);
        conv_row(W1c + (size_t)r1 * NN, W1bf + (size_t)(NN + r1) * NN,     r1, t);
    } else {
        const int b = gb - NCONV;
        l0_block(inp + (size_t)b * DBLK, W0, b0, h0, e0, mmax, b, t);
    }
}

// ---- P2/P4: layer1. grid (dd=16, bt=16, ct=4), 512 thr (8 waves).
// Tile = 16 batch rows x 32 cols. Waves take interleaved 32-wide K-chunks
// (c = w, w+8, ...); LDS combine over 8; one output per thread in epilogue.
// h1 written as bf16.
__global__ void __launch_bounds__(512, 8)
k_layer1(const unsigned short* __restrict__ h0,
         const unsigned short* __restrict__ W1b,
         const float* __restrict__ b1,
         const unsigned short* __restrict__ e0,
         const float* __restrict__ mmax,
         unsigned short* __restrict__ h1,
         float* __restrict__ g1) {
    const int dd    = blockIdx.x;
    const int bt    = blockIdx.y;
    const int ct    = blockIdx.z;
    const int w     = threadIdx.x >> 6;      // 0..7
    const int lane  = threadIdx.x & 63;
    const int brow0 = bt * 16;
    const int arow  = brow0 + (lane & 15);
    const int koff  = (lane >> 4) * 8;
    const int ncol  = lane & 15;
    const int col0  = dd * OB + ct * 32;

    f32x4 acc[2], acc2[2];
    #pragma unroll
    for (int nt = 0; nt < 2; ++nt) {
        acc[nt]  = (f32x4){0.f, 0.f, 0.f, 0.f};
        acc2[nt] = (f32x4){0.f, 0.f, 0.f, 0.f};
    }

    const unsigned short* Ab = h0 + (size_t)arow * NN + koff;
    const unsigned short* Bb[2];
    #pragma unroll
    for (int nt = 0; nt < 2; ++nt)
        Bb[nt] = W1b + (size_t)(col0 + nt * 16 + ncol) * NN + koff;

    // GEMM: wave w takes chunks c = w, w+8, ... of the (dd+1)*4 chunks
    const int nch = (dd + 1) * 4;
    #pragma unroll 2
    for (int c = w; c < nch; c += 8) {
        const int k = c * 32;
        bf16x8 a  = *(const bf16x8*)(Ab + k);
        bf16x8 b0v = *(const bf16x8*)(Bb[0] + k);
        bf16x8 b1v = *(const bf16x8*)(Bb[1] + k);
        acc[0] = __builtin_amdgcn_mfma_f32_16x16x32_bf16(a, b0v, acc[0], 0, 0, 0);
        acc[1] = __builtin_amdgcn_mfma_f32_16x16x32_bf16(a, b1v, acc[1], 0, 0, 0);
    }

    // grad matvec over the 128-wide diagonal block: waves 0..3, one 32-chunk each
    if (w < 4) {
        const int k2 = dd * OB + w * 32;
        bf16x8 a = *(const bf16x8*)(e0 + (size_t)arow * NN + koff + k2);
        acc2[0] = __builtin_amdgcn_mfma_f32_16x16x32_bf16(a, *(const bf16x8*)(Bb[0] + k2), acc2[0], 0, 0, 0);
        acc2[1] = __builtin_amdgcn_mfma_f32_16x16x32_bf16(a, *(const bf16x8*)(Bb[1] + k2), acc2[1], 0, 0, 0);
    }

    __shared__ float ls1[8][2][64][4];
    __shared__ float ls2[4][2][64][4];
    #pragma unroll
    for (int nt = 0; nt < 2; ++nt)
        *(f32x4*)&ls1[w][nt][lane][0] = acc[nt];
    if (w < 4) {
        #pragma unroll
        for (int nt = 0; nt < 2; ++nt)
            *(f32x4*)&ls2[w][nt][lane][0] = acc2[nt];
    }
    __syncthreads();

    {
        const int o  = threadIdx.x;            // 0..511 output index in tile
        const int rr = o >> 5;                 // 0..15 row in tile
        const int cc = o & 31;                 // 0..31 col in tile
        const int nt = cc >> 4;
        const int r  = rr & 3;
        const int ls = (rr >> 2) * 16 + (cc & 15);
        float S = 0.f, S2 = 0.f;
        #pragma unroll
        for (int ww = 0; ww < 8; ++ww) S += ls1[ww][nt][ls][r];
        #pragma unroll
        for (int ww = 0; ww < 4; ++ww) S2 += ls2[ww][nt][ls][r];
        const int j    = col0 + cc;
        const int brow = brow0 + rr;
        const float pre = S + b1[j];
        h1[(size_t)brow * NN + j] = f2bf(tanhf(pre));
        g1[(size_t)brow * NN + j] = logf(S2) + mmax[brow * DBLK + dd] + log_tanh_grad(pre);
    }
}

// ---- final-layer compute for one batch row (256 threads). h1 is bf16.
__device__ __forceinline__ float final_compute(const unsigned short* __restrict__ h1,
                                               const float* __restrict__ g1,
                                               const float* __restrict__ W2,
                                               int b, int t,
                                               float* sh, float* gf, float* sx) {
    const int wave = t >> 6;
    const int lane = t & 63;
    {
        const int k = t * 8;                   // one ushort8 per thread covers NN
        ushort8 hv = *(const ushort8*)(h1 + (size_t)b * NN + k);
        float4 f0, f1;
        f0.x = bf2f(hv[0]); f0.y = bf2f(hv[1]); f0.z = bf2f(hv[2]); f0.w = bf2f(hv[3]);
        f1.x = bf2f(hv[4]); f1.y = bf2f(hv[5]); f1.z = bf2f(hv[6]); f1.w = bf2f(hv[7]);
        *(float4*)(sh + k)     = f0;
        *(float4*)(sh + k + 4) = f1;
    }
    __syncthreads();

    #pragma unroll
    for (int q = 0; q < 4; ++q) {
        const int dd = wave * 4 + q;
        const float* w2r = W2 + (size_t)dd * NN;
        const int kend = (dd + 1) * OB;
        float s = 0.f;
        for (int k = lane * 4; k < kend; k += 64 * 4) {
            float4 hv = *(const float4*)(sh + k);
            float4 wv = *(const float4*)(w2r + k);
            s += hv.x * wv.x + hv.y * wv.y + hv.z * wv.z + hv.w * wv.w;
        }
        #pragma unroll
        for (int off = 32; off > 0; off >>= 1) s += __shfl_xor(s, off);
        float v0 = g1[(size_t)b * NN + dd * OB + lane];
        float v1 = g1[(size_t)b * NN + dd * OB + 64 + lane];
        float m = fmaxf(v0, v1);
        #pragma unroll
        for (int off = 32; off > 0; off >>= 1) m = fmaxf(m, __shfl_xor(m, off));
        float e = __expf(v0 - m) * w2r[dd * OB + lane]
                + __expf(v1 - m) * w2r[dd * OB + 64 + lane];
        #pragma unroll
        for (int off = 32; off > 0; off >>= 1) e += __shfl_xor(e, off);
        if (lane == 0) {
            sx[dd] = s;
            gf[dd] = logf(e) + m;
        }
    }
    __syncthreads();
    float ld = 0.f;
    #pragma unroll
    for (int dd = 0; dd < DBLK; ++dd) ld += gf[dd];
    return ld;
}

// ---- P3: final of flow 0 + layer0 of flow 1 (block b = batch row b)
__global__ void k_final0_l0(const unsigned short* __restrict__ h1,
                            const float* __restrict__ g1,
                            const float* __restrict__ W2,   // flow 0
                            const float* __restrict__ W0,   // flow 1
                            const float* __restrict__ b0,   // flow 1
                            unsigned short* __restrict__ h0,
                            unsigned short* __restrict__ e0,
                            float* __restrict__ mmax,
                            float* __restrict__ ld0) {
    __shared__ float sh[NN];
    __shared__ float gf[DBLK];
    __shared__ float sx[DBLK];
    const int b = blockIdx.x;
    const int t = threadIdx.x;
    float ld = final_compute(h1, g1, W2, b, t, sh, gf, sx);
    if (t == 0) ld0[b] = ld;
    l0_block(sx, W0, b0, h0, e0, mmax, b, t);
}

// ---- P5: final of flow 1 -> d_out
__global__ void k_final1(const unsigned short* __restrict__ h1,
                         const float* __restrict__ g1,
                         const float* __restrict__ W2,   // flow 1
                         const float* __restrict__ ld0,
                         float* __restrict__ out_final,
                         float* __restrict__ ld_final) {
    __shared__ float sh[NN];
    __shared__ float gf[DBLK];
    __shared__ float sx[DBLK];
    const int b = blockIdx.x;
    const int t = threadIdx.x;
    float ld = final_compute(h1, g1, W2, b, t, sh, gf, sx);
    if (t < DBLK) out_final[b * DBLK + t] = sx[t];
    if (t == 0) ld_final[b] = ld + ld0[b];
}

extern "C" void kernel_launch(void* const* d_in, const int* in_sizes, int n_in,
                              void* d_out, int out_size, void* d_ws, size_t ws_size,
                              hipStream_t stream) {
    const float* inp   = (const float*)d_in[0];
    const float* W0[2] = {(const float*)d_in[1], (const float*)d_in[6]};
    const float* W1[2] = {(const float*)d_in[2], (const float*)d_in[7]};
    const float* W2[2] = {(const float*)d_in[3], (const float*)d_in[8]};
    const float* b0[2] = {(const float*)d_in[4], (const float*)d_in[9]};
    const float* b1[2] = {(const float*)d_in[5], (const float*)d_in[10]};

    char* w = (char*)d_ws;
    size_t off = 0;
    unsigned short* W1bf = (unsigned short*)(w + off); off += (size_t)2 * NN * NN * 2; // 16 MB
    unsigned short* h0b  = (unsigned short*)(w + off); off += (size_t)BATCH * NN * 2;  // 1 MB
    unsigned short* e0b  = (unsigned short*)(w + off); off += (size_t)BATCH * NN * 2;  // 1 MB
    float* mmax = (float*)(w + off); off += (size_t)BATCH * DBLK * 4;
    unsigned short* h1 = (unsigned short*)(w + off); off += (size_t)BATCH * NN * 2;    // 1 MB
    float* g1   = (float*)(w + off); off += (size_t)BATCH * NN * 4;                    // 2 MB
    float* ld0  = (float*)(w + off); off += (size_t)BATCH * 4;

    float* out_final = (float*)d_out;                 // (256,16)
    float* ld_final  = (float*)d_out + BATCH * DBLK;  // (256,)

    // P1: convert both W1 + layer0 of flow 0
    k_prep<<<dim3(NCONV + BATCH), dim3(256), 0, stream>>>(
        W1[0], W1[1], W1bf, inp, W0[0], b0[0], h0b, e0b, mmax);

    // P2: layer1 flow 0
    k_layer1<<<dim3(DBLK, 16, 4), dim3(512), 0, stream>>>(
        h0b, W1bf, b1[0], e0b, mmax, h1, g1);

    // P3: final flow 0 + layer0 flow 1
    k_final0_l0<<<dim3(BATCH), dim3(256), 0, stream>>>(
        h1, g1, W2[0], W0[1], b0[1], h0b, e0b, mmax, ld0);

    // P4: layer1 flow 1
    k_layer1<<<dim3(DBLK, 16, 4), dim3(512), 0, stream>>>(
        h0b, W1bf + (size_t)NN * NN, b1[1], e0b, mmax, h1, g1);

    // P5: final flow 1
    k_final1<<<dim3(BATCH), dim3(256), 0, stream>>>(
        h1, g1, W2[1], ld0, out_final, ld_final);
}